// Round 2
// baseline (197.217 us; speedup 1.0000x reference)
//
#include <hip/hip_runtime.h>

// FBP fan-beam: weight -> truncated ramp filter (fp16 pair-packed, coef folded)
// -> single backprojection pass: 32x8 pixel tile x ALL 32 batches per block,
// per-(tile,view) 64-bin staging window (prep kernel), atomicAdd epilogue.
// R2: bp staging is a 4-slot LDS ring, depth-3 counted-vmcnt pipeline with
// raw s_barrier (no vmcnt(0) drain per view).
#define VIEWS 160
#define DETS  640
#define H_IMG 416
#define W_IMG 416
#define BATCH 32

constexpr double D_IMG_D  = 0.006641;
constexpr double D_DET_D  = 0.012858;
constexpr double S2R_D    = 5.95;
constexpr double D2R_D    = 4.906;
constexpr double VIRDET_D = D_DET_D * S2R_D / (S2R_D + D2R_D);
constexpr double PI_D     = 3.14159265358979323846;

typedef __fp16 __attribute__((ext_vector_type(2))) h2f;

#define TILES_X 13
#define TILES_Y 52
#define NTILES  (TILES_X * TILES_Y)   // 676
#define NB      64                    // staged bins per (tile, view)

// ---------------------------------------------------------------------------
// Kernel 0: per-view constants + per-(tile,view) stage-window start.
// idx is fractional-linear in (X,Y) with U>0 -> extremes at tile corners.
// Max span over a 32x8 tile <= 1.40/px * 38 px ~ 54 bins; NB=64 with guard 2
// and even alignment leaves >=5 bins margin. bs even -> 16B-aligned staging.
// ---------------------------------------------------------------------------
__global__ __launch_bounds__(160) void prep_kernel(float* __restrict__ vcs,
                                                   int* __restrict__ bs_tab) {
    int v    = threadIdx.x;
    int tile = blockIdx.x;
    float dang = (float)(0.009817477 * 4.0);
    float beta = dang * (float)v;
    float cb = cosf(beta), sb = sinf(beta);
    float K  = (float)(S2R_D / VIRDET_D);
    if (tile == 0) {
        ((float4*)vcs)[v] = make_float4(cb, sb, -K * sb, K * cb);
    }
    int ty = tile / TILES_X, tx = tile - ty * TILES_X;
    float XL = ((float)(tx * 32) - 207.5f) * (float)D_IMG_D;
    float XR = ((float)(tx * 32 + 31) - 207.5f) * (float)D_IMG_D;
    float YT = (207.5f - (float)(ty * 8)) * (float)D_IMG_D;
    float YB = (207.5f - (float)(ty * 8 + 7)) * (float)D_IMG_D;
    float m = 1e30f;
#define CORNER(Xc, Yc) { \
        float r_ = -(Xc) * sb + (Yc) * cb; \
        float U_ = (float)S2R_D - (Xc) * cb - (Yc) * sb; \
        float ix = fmaf(K, r_ / U_, 319.5f); \
        m = fminf(m, ix); }
    CORNER(XL, YT); CORNER(XR, YT); CORNER(XL, YB); CORNER(XR, YB);
#undef CORNER
    int bs = (int)floorf(m) - 2;
    bs = max(0, min(DETS - NB, bs)) & ~1;
    bs_tab[tile * VIEWS + v] = bs;
}

// ---------------------------------------------------------------------------
// Kernel 1: weighting + TRUNCATED ramp filter (unchanged conv). Epilogue
// interleaves the two pair-columns via LDS and stores layout
// pf uints: [view][grp8][bin][q]  (grp = group4, q = sub; pair p = 2g+q,
// batches (2p, 2p+1)) -> per (view,grp) a contiguous 5120B row, and per bin
// a uint2 = {pair 2g, pair 2g+1} for the bp ds_read2_b64 gather.
// ---------------------------------------------------------------------------
#define FT 320
#define RPAD 24            // f4 pad each side (96 floats)
#define RSTR 209           // padded row stride in f4 (24 + 160 + 25)
__global__ __launch_bounds__(FT) void filter_kernel(
    const float* __restrict__ proj, const float* __restrict__ w,
    const float* __restrict__ filt, unsigned int* __restrict__ pf) {
    __shared__ float4 s_in[4 * RSTR];      // 13376 B zero-padded rows
    __shared__ float  s_f[2 * DETS];       // 5120 B
    __shared__ unsigned int s_out[2 * DETS]; // 5120 B reinterleave buffer

    int t = threadIdx.x;
    int g = blockIdx.x;                 // g = group4*160 + v, group4 in [0,8)
    int group4 = g / 160;
    int v = g - group4 * 160;

    for (int e = t; e < 4 * RSTR; e += FT) {
        int ri = e / RSTR, c4 = e - ri * RSTR;
        float4 pv = make_float4(0.f, 0.f, 0.f, 0.f);
        if (c4 >= RPAD && c4 < RPAD + 160) {
            int b = group4 * 4 + ri;
            pv = ((const float4*)(proj + ((size_t)b * VIEWS + v) * DETS))[c4 - RPAD];
            float4 wv = ((const float4*)w)[c4 - RPAD];
            pv.x *= wv.x; pv.y *= wv.y; pv.z *= wv.z; pv.w *= wv.w;
        }
        s_in[e] = pv;
    }
    for (int e = t; e < 2 * DETS; e += FT) s_f[e] = (e < 2 * DETS - 1) ? filt[e] : 0.f;
    __syncthreads();

    int sub = (t >= 160) ? 1 : 0;       // sub 0: rows 0,1 (pair 2g); sub 1: rows 2,3
    int tj  = t - sub * 160;

    const float4* f4  = (const float4*)s_f;
    const float4* in4 = &s_in[sub * 2 * RSTR + tj];
    float4 o0 = {0,0,0,0}, o1 = {0,0,0,0};   // even row, odd row
    float4 fp = f4[135];                // wave-uniform window start
    #pragma unroll 2
    for (int u = 0; u < 50; ++u) {
        float4 fn = f4[136 + u];        // wave-uniform
        {
            float4 iv = in4[0 * RSTR + u];
            o0.x = fmaf(iv.x, fp.w, o0.x); o0.x = fmaf(iv.y, fn.x, o0.x);
            o0.x = fmaf(iv.z, fn.y, o0.x); o0.x = fmaf(iv.w, fn.z, o0.x);
            o0.y = fmaf(iv.x, fp.z, o0.y); o0.y = fmaf(iv.y, fp.w, o0.y);
            o0.y = fmaf(iv.z, fn.x, o0.y); o0.y = fmaf(iv.w, fn.y, o0.y);
            o0.z = fmaf(iv.x, fp.y, o0.z); o0.z = fmaf(iv.y, fp.z, o0.z);
            o0.z = fmaf(iv.z, fp.w, o0.z); o0.z = fmaf(iv.w, fn.x, o0.z);
            o0.w = fmaf(iv.x, fp.x, o0.w); o0.w = fmaf(iv.y, fp.y, o0.w);
            o0.w = fmaf(iv.z, fp.z, o0.w); o0.w = fmaf(iv.w, fp.w, o0.w);
        }
        {
            float4 iv = in4[1 * RSTR + u];
            o1.x = fmaf(iv.x, fp.w, o1.x); o1.x = fmaf(iv.y, fn.x, o1.x);
            o1.x = fmaf(iv.z, fn.y, o1.x); o1.x = fmaf(iv.w, fn.z, o1.x);
            o1.y = fmaf(iv.x, fp.z, o1.y); o1.y = fmaf(iv.y, fp.w, o1.y);
            o1.y = fmaf(iv.z, fn.x, o1.y); o1.y = fmaf(iv.w, fn.y, o1.y);
            o1.z = fmaf(iv.x, fp.y, o1.z); o1.z = fmaf(iv.y, fp.z, o1.z);
            o1.z = fmaf(iv.z, fp.w, o1.z); o1.z = fmaf(iv.w, fn.x, o1.z);
            o1.w = fmaf(iv.x, fp.x, o1.w); o1.w = fmaf(iv.y, fp.y, o1.w);
            o1.w = fmaf(iv.z, fp.z, o1.w); o1.w = fmaf(iv.w, fp.w, o1.w);
        }
        fp = fn;
    }

    // fold final scale; pair uint = pkrtz(even, odd); stash per-column in LDS
    float coef = (float)((PI_D / (double)VIEWS) * S2R_D * S2R_D);
    auto h0 = __builtin_amdgcn_cvt_pkrtz(o0.x * coef, o1.x * coef);
    auto h1 = __builtin_amdgcn_cvt_pkrtz(o0.y * coef, o1.y * coef);
    auto h2 = __builtin_amdgcn_cvt_pkrtz(o0.z * coef, o1.z * coef);
    auto h3 = __builtin_amdgcn_cvt_pkrtz(o0.w * coef, o1.w * coef);
    uint4 pk = make_uint4(__builtin_bit_cast(unsigned int, h0),
                          __builtin_bit_cast(unsigned int, h1),
                          __builtin_bit_cast(unsigned int, h2),
                          __builtin_bit_cast(unsigned int, h3));
    *(uint4*)&s_out[sub * DETS + 4 * tj] = pk;
    __syncthreads();

    // reinterleave: thread t emits bins (2t, 2t+1) x q{0,1} as one uint4
    unsigned int a0 = s_out[2 * t],        a1 = s_out[2 * t + 1];
    unsigned int b0 = s_out[DETS + 2 * t], b1 = s_out[DETS + 2 * t + 1];
    uint4 o = make_uint4(a0, b0, a1, b1);
    ((uint4*)(pf + ((size_t)v * 8 + group4) * (2 * DETS)))[t] = o;
}

// ---------------------------------------------------------------------------
// Kernel 2: backprojection, one view-half (80 views). Block = 32x8 pixel tile
// x 32 batches (grid 13x52x2 = 1352). Staging: 4-slot LDS ring (4096 B/slot),
// depth-3 pipeline. Per iter: s_waitcnt vmcnt(2) (own stage for view c done,
// 2 newer stay in flight) -> raw s_barrier (all waves' stage(c) visible) ->
// issue stage(c+3) into slot (c+3)&3 (WAR-safe: that slot was last read at
// iter c-1, which the barrier just fenced) -> gather. Tail re-stages view 79
// (clamped) to keep vmcnt accounting uniform. Geometry/weights/drain cadence
// bit-identical to R1. atomicAdd epilogue into memset-zeroed out.
// ---------------------------------------------------------------------------
__device__ __forceinline__ void gld_lds16(const char* g, char* l) {
    __builtin_amdgcn_global_load_lds(
        (const __attribute__((address_space(1))) unsigned int*)g,
        (__attribute__((address_space(3))) unsigned int*)l, 16, 0, 0);
}

__global__ __launch_bounds__(256, 8) void bp_kernel(
    const unsigned int* __restrict__ pf, const float* __restrict__ vcs,
    const int* __restrict__ bs_tab, float* __restrict__ out) {
    __shared__ alignas(16) unsigned int s_buf[4 * 1024];  // 4 slots x 4096 B

    int t    = threadIdx.x;
    int half = blockIdx.z;
    int tile = blockIdx.y * TILES_X + blockIdx.x;
    int x    = blockIdx.x * 32 + (t & 31);
    int y    = blockIdx.y * 8 + (t >> 5);

    float X  = ((float)x - 207.5f) * (float)D_IMG_D;
    float Yv = (207.5f - (float)y) * (float)D_IMG_D;

    int vbase = half * (VIEWS / 2);
    const float4* vc4 = (const float4*)vcs + vbase;
    const int*    bsp = bs_tab + tile * VIEWS + vbase;
    const char*   pfb = (const char*)pf + (size_t)vbase * 40960; // 8*640*8 B/view
    int  goff  = (t >> 5) * (DETS * 8) + (t & 31) * 16;  // per-lane src offset
    int  ldoff = (t >> 6) << 10;                         // wave-uniform dst base

    float acc[32];
    #pragma unroll
    for (int b = 0; b < 32; ++b) acc[b] = 0.f;
    h2f hacc[16];
    #pragma unroll
    for (int p = 0; p < 16; ++p) hacc[p] = (h2f)0.f;

    // prologue: stage views 0..2 into slots 0..2
    #pragma unroll
    for (int d = 0; d < 3; ++d) {
        int bsd = bsp[d];
        gld_lds16(pfb + (size_t)d * 40960 + (size_t)bsd * 8 + goff,
                  (char*)s_buf + (d << 12) + ldoff);
    }

    for (int c = 0; c < VIEWS / 2; ++c) {
        // own stage(c) complete (2 newer loads may remain in flight)
        asm volatile("s_waitcnt vmcnt(2)" ::: "memory");
        __builtin_amdgcn_s_barrier();          // all waves' stage(c) visible
        __builtin_amdgcn_sched_barrier(0);

        {   // issue stage for view c+3 (clamped tail keeps vmcnt uniform)
            int vn  = min(c + 3, VIEWS / 2 - 1);
            int bsn = bsp[vn];
            gld_lds16(pfb + (size_t)vn * 40960 + (size_t)bsn * 8 + goff,
                      (char*)s_buf + (((c + 3) & 3) << 12) + ldoff);
        }

        float4 a  = vc4[c];
        int    bsc = bsp[c];
        float U   = fmaf(-X, a.x, fmaf(-Yv, a.y, (float)S2R_D));
        float num = fmaf(X, a.z, Yv * a.w);
        float ru   = __builtin_amdgcn_rcpf(U);
        float idx  = fmaf(num, ru, 319.5f);
        float idxc = __builtin_amdgcn_fmed3f(idx, 0.f, 639.f);
        float i0f  = fminf(idxc, 638.0f);
        int   i0   = (int)i0f;
        float frac = idxc - truncf(i0f);
        float w2   = ru * ru;
        float wgt  = (idx == idxc) ? w2 : 0.f;
        float w1f  = wgt * frac;
        float w0f  = wgt - w1f;
        h2f w0h = __builtin_amdgcn_cvt_pkrtz(w0f, w0f);
        h2f w1h = __builtin_amdgcn_cvt_pkrtz(w1f, w1f);
        int bl = min(max(i0 - bsc, 0), NB - 2);  // window-safe (wgt=0 if invalid)
        const uint2* L = (const uint2*)((const char*)s_buf + ((c & 3) << 12)) + bl;
        #pragma unroll
        for (int gg = 0; gg < 8; ++gg) {
            uint2 A = L[gg * NB];        // bin bl  : pairs (2g, 2g+1)
            uint2 B = L[gg * NB + 1];    // bin bl+1: pairs (2g, 2g+1)
            h2f pa = __builtin_bit_cast(h2f, A.x);
            h2f pb = __builtin_bit_cast(h2f, B.x);
            h2f pc = __builtin_bit_cast(h2f, A.y);
            h2f pd = __builtin_bit_cast(h2f, B.y);
            hacc[2 * gg]     = __builtin_elementwise_fma(pa, w0h, hacc[2 * gg]);
            hacc[2 * gg]     = __builtin_elementwise_fma(pb, w1h, hacc[2 * gg]);
            hacc[2 * gg + 1] = __builtin_elementwise_fma(pc, w0h, hacc[2 * gg + 1]);
            hacc[2 * gg + 1] = __builtin_elementwise_fma(pd, w1h, hacc[2 * gg + 1]);
        }
        if ((c & 7) == 7) {             // drain fp16 partials to fp32
            #pragma unroll
            for (int gg = 0; gg < 8; ++gg) {
                acc[4 * gg + 0] += (float)hacc[2 * gg].x;
                acc[4 * gg + 1] += (float)hacc[2 * gg].y;
                acc[4 * gg + 2] += (float)hacc[2 * gg + 1].x;
                acc[4 * gg + 3] += (float)hacc[2 * gg + 1].y;
                hacc[2 * gg] = (h2f)0.f; hacc[2 * gg + 1] = (h2f)0.f;
            }
        }
    }

    float* ob = out + (size_t)y * W_IMG + x;
    #pragma unroll
    for (int b = 0; b < 32; ++b)
        unsafeAtomicAdd(ob + (size_t)b * (H_IMG * W_IMG), acc[b]);
}

// ---------------------------------------------------------------------------
extern "C" void kernel_launch(void* const* d_in, const int* in_sizes, int n_in,
                              void* d_out, int out_size, void* d_ws, size_t ws_size,
                              hipStream_t stream) {
    const float* proj = (const float*)d_in[0];   // [32,1,160,640]
    const float* w    = (const float*)d_in[1];   // [640]
    const float* filt = (const float*)d_in[2];   // [1279]
    float* out = (float*)d_out;                  // [32,1,416,416]

    float*        vcs    = (float*)d_ws;                         // 2560 B
    int*          bs_tab = (int*)((char*)d_ws + 4096);           // 432,640 B
    unsigned int* pf     = (unsigned int*)((char*)d_ws + 4096 + 432640); // 6.55 MB

    hipMemsetAsync(d_out, 0, (size_t)BATCH * H_IMG * W_IMG * sizeof(float), stream);
    prep_kernel<<<NTILES, 160, 0, stream>>>(vcs, bs_tab);
    filter_kernel<<<(BATCH / 4) * VIEWS, FT, 0, stream>>>(proj, w, filt, pf);
    bp_kernel<<<dim3(TILES_X, TILES_Y, 2), 256, 0, stream>>>(pf, vcs, bs_tab, out);
}

// Round 3
// 190.691 us; speedup vs baseline: 1.0342x; 1.0342x over previous
//
#include <hip/hip_runtime.h>

// FBP fan-beam: weight -> truncated ramp filter (fp16 pair-packed, coef folded)
// -> single backprojection pass: 32x8 pixel tile x ALL 32 batches per block,
// per-(tile,view) 64-bin staging window, atomicAdd epilogue.
// R3: views split 3 ways (grid 2028 = 7.92 blocks/CU, ~all resident, even
// balance); R1-style double-buffered staging (measured best); memset+prep
// fused into init_kernel (3 dispatches total).
#define VIEWS 160
#define DETS  640
#define H_IMG 416
#define W_IMG 416
#define BATCH 32

constexpr double D_IMG_D  = 0.006641;
constexpr double D_DET_D  = 0.012858;
constexpr double S2R_D    = 5.95;
constexpr double D2R_D    = 4.906;
constexpr double VIRDET_D = D_DET_D * S2R_D / (S2R_D + D2R_D);
constexpr double PI_D     = 3.14159265358979323846;

typedef __fp16 __attribute__((ext_vector_type(2))) h2f;

#define TILES_X 13
#define TILES_Y 52
#define NTILES  (TILES_X * TILES_Y)   // 676
#define NB      64                    // staged bins per (tile, view)
#define ZSPLIT  3                     // view chunks (54/53/53)

// ---------------------------------------------------------------------------
// Kernel 0: init = per-view constants + per-(tile,view) stage-window start
// + zero the output (replaces hipMemsetAsync; saves a dispatch).
// Block = tile (676 blocks x 256 threads); each thread zeros exactly 8 float4
// of out (676*256*8*4 = 5,537,792 floats = BATCH*H*W).
// idx is fractional-linear in (X,Y) with U>0 -> extremes at tile corners.
// Max span over a 32x8 tile <= 1.40/px * 38 px ~ 54 bins; NB=64 with guard 2
// and even alignment leaves >=5 bins margin. bs even -> 16B-aligned staging.
// ---------------------------------------------------------------------------
__global__ __launch_bounds__(256) void init_kernel(float* __restrict__ vcs,
                                                   int* __restrict__ bs_tab,
                                                   float4* __restrict__ out4) {
    int t    = threadIdx.x;
    int tile = blockIdx.x;
    if (t < VIEWS) {
        int v = t;
        float dang = (float)(0.009817477 * 4.0);
        float beta = dang * (float)v;
        float cb = cosf(beta), sb = sinf(beta);
        float K  = (float)(S2R_D / VIRDET_D);
        if (tile == 0) {
            ((float4*)vcs)[v] = make_float4(cb, sb, -K * sb, K * cb);
        }
        int ty = tile / TILES_X, tx = tile - ty * TILES_X;
        float XL = ((float)(tx * 32) - 207.5f) * (float)D_IMG_D;
        float XR = ((float)(tx * 32 + 31) - 207.5f) * (float)D_IMG_D;
        float YT = (207.5f - (float)(ty * 8)) * (float)D_IMG_D;
        float YB = (207.5f - (float)(ty * 8 + 7)) * (float)D_IMG_D;
        float m = 1e30f;
#define CORNER(Xc, Yc) { \
        float r_ = -(Xc) * sb + (Yc) * cb; \
        float U_ = (float)S2R_D - (Xc) * cb - (Yc) * sb; \
        float ix = fmaf(K, r_ / U_, 319.5f); \
        m = fminf(m, ix); }
        CORNER(XL, YT); CORNER(XR, YT); CORNER(XL, YB); CORNER(XR, YB);
#undef CORNER
        int bs = (int)floorf(m) - 2;
        bs = max(0, min(DETS - NB, bs)) & ~1;
        bs_tab[tile * VIEWS + v] = bs;
    }
    // zero output slice (coalesced: 8 x float4 per thread)
    size_t base = (size_t)tile * 2048 + t;
    float4 z = make_float4(0.f, 0.f, 0.f, 0.f);
    #pragma unroll
    for (int i = 0; i < 8; ++i) out4[base + (size_t)i * 256] = z;
}

// ---------------------------------------------------------------------------
// Kernel 1: weighting + TRUNCATED ramp filter (unchanged conv). Epilogue
// interleaves the two pair-columns via LDS and stores layout
// pf uints: [view][grp8][bin][q]  (grp = group4, q = sub; pair p = 2g+q,
// batches (2p, 2p+1)) -> per (view,grp) a contiguous 5120B row, and per bin
// a uint2 = {pair 2g, pair 2g+1} for the bp ds_read2_b64 gather.
// ---------------------------------------------------------------------------
#define FT 320
#define RPAD 24            // f4 pad each side (96 floats)
#define RSTR 209           // padded row stride in f4 (24 + 160 + 25)
__global__ __launch_bounds__(FT) void filter_kernel(
    const float* __restrict__ proj, const float* __restrict__ w,
    const float* __restrict__ filt, unsigned int* __restrict__ pf) {
    __shared__ float4 s_in[4 * RSTR];      // 13376 B zero-padded rows
    __shared__ float  s_f[2 * DETS];       // 5120 B
    __shared__ unsigned int s_out[2 * DETS]; // 5120 B reinterleave buffer

    int t = threadIdx.x;
    int g = blockIdx.x;                 // g = group4*160 + v, group4 in [0,8)
    int group4 = g / 160;
    int v = g - group4 * 160;

    for (int e = t; e < 4 * RSTR; e += FT) {
        int ri = e / RSTR, c4 = e - ri * RSTR;
        float4 pv = make_float4(0.f, 0.f, 0.f, 0.f);
        if (c4 >= RPAD && c4 < RPAD + 160) {
            int b = group4 * 4 + ri;
            pv = ((const float4*)(proj + ((size_t)b * VIEWS + v) * DETS))[c4 - RPAD];
            float4 wv = ((const float4*)w)[c4 - RPAD];
            pv.x *= wv.x; pv.y *= wv.y; pv.z *= wv.z; pv.w *= wv.w;
        }
        s_in[e] = pv;
    }
    for (int e = t; e < 2 * DETS; e += FT) s_f[e] = (e < 2 * DETS - 1) ? filt[e] : 0.f;
    __syncthreads();

    int sub = (t >= 160) ? 1 : 0;       // sub 0: rows 0,1 (pair 2g); sub 1: rows 2,3
    int tj  = t - sub * 160;

    const float4* f4  = (const float4*)s_f;
    const float4* in4 = &s_in[sub * 2 * RSTR + tj];
    float4 o0 = {0,0,0,0}, o1 = {0,0,0,0};   // even row, odd row
    float4 fp = f4[135];                // wave-uniform window start
    #pragma unroll 2
    for (int u = 0; u < 50; ++u) {
        float4 fn = f4[136 + u];        // wave-uniform
        {
            float4 iv = in4[0 * RSTR + u];
            o0.x = fmaf(iv.x, fp.w, o0.x); o0.x = fmaf(iv.y, fn.x, o0.x);
            o0.x = fmaf(iv.z, fn.y, o0.x); o0.x = fmaf(iv.w, fn.z, o0.x);
            o0.y = fmaf(iv.x, fp.z, o0.y); o0.y = fmaf(iv.y, fp.w, o0.y);
            o0.y = fmaf(iv.z, fn.x, o0.y); o0.y = fmaf(iv.w, fn.y, o0.y);
            o0.z = fmaf(iv.x, fp.y, o0.z); o0.z = fmaf(iv.y, fp.z, o0.z);
            o0.z = fmaf(iv.z, fp.w, o0.z); o0.z = fmaf(iv.w, fn.x, o0.z);
            o0.w = fmaf(iv.x, fp.x, o0.w); o0.w = fmaf(iv.y, fp.y, o0.w);
            o0.w = fmaf(iv.z, fp.z, o0.w); o0.w = fmaf(iv.w, fp.w, o0.w);
        }
        {
            float4 iv = in4[1 * RSTR + u];
            o1.x = fmaf(iv.x, fp.w, o1.x); o1.x = fmaf(iv.y, fn.x, o1.x);
            o1.x = fmaf(iv.z, fn.y, o1.x); o1.x = fmaf(iv.w, fn.z, o1.x);
            o1.y = fmaf(iv.x, fp.z, o1.y); o1.y = fmaf(iv.y, fp.w, o1.y);
            o1.y = fmaf(iv.z, fn.x, o1.y); o1.y = fmaf(iv.w, fn.y, o1.y);
            o1.z = fmaf(iv.x, fp.y, o1.z); o1.z = fmaf(iv.y, fp.z, o1.z);
            o1.z = fmaf(iv.z, fp.w, o1.z); o1.z = fmaf(iv.w, fn.x, o1.z);
            o1.w = fmaf(iv.x, fp.x, o1.w); o1.w = fmaf(iv.y, fp.y, o1.w);
            o1.w = fmaf(iv.z, fp.z, o1.w); o1.w = fmaf(iv.w, fp.w, o1.w);
        }
        fp = fn;
    }

    // fold final scale; pair uint = pkrtz(even, odd); stash per-column in LDS
    float coef = (float)((PI_D / (double)VIEWS) * S2R_D * S2R_D);
    auto h0 = __builtin_amdgcn_cvt_pkrtz(o0.x * coef, o1.x * coef);
    auto h1 = __builtin_amdgcn_cvt_pkrtz(o0.y * coef, o1.y * coef);
    auto h2 = __builtin_amdgcn_cvt_pkrtz(o0.z * coef, o1.z * coef);
    auto h3 = __builtin_amdgcn_cvt_pkrtz(o0.w * coef, o1.w * coef);
    uint4 pk = make_uint4(__builtin_bit_cast(unsigned int, h0),
                          __builtin_bit_cast(unsigned int, h1),
                          __builtin_bit_cast(unsigned int, h2),
                          __builtin_bit_cast(unsigned int, h3));
    *(uint4*)&s_out[sub * DETS + 4 * tj] = pk;
    __syncthreads();

    // reinterleave: thread t emits bins (2t, 2t+1) x q{0,1} as one uint4
    unsigned int a0 = s_out[2 * t],        a1 = s_out[2 * t + 1];
    unsigned int b0 = s_out[DETS + 2 * t], b1 = s_out[DETS + 2 * t + 1];
    uint4 o = make_uint4(a0, b0, a1, b1);
    ((uint4*)(pf + ((size_t)v * 8 + group4) * (2 * DETS)))[t] = o;
}

// ---------------------------------------------------------------------------
// Kernel 2: backprojection over one view-chunk (54/53/53 views). Block =
// 32x8 pixel tile x 32 batches (grid 13x52x3 = 2028 -> 7.92 blocks/CU, all
// resident at __launch_bounds__(256,8): 8KB LDS, 32 VGPR). Per view: stage
// the tile's 64-bin window (4096B, double-buffered global_load_lds), geometry
// once per pixel, gather 8x ds_read2_b64 + 32 v_pk_fma_f16. fp16 pair accs
// drained to fp32 every 8 views + epilogue drain. atomicAdd epilogue.
// ---------------------------------------------------------------------------
__device__ __forceinline__ void gld_lds16(const char* g, char* l) {
    __builtin_amdgcn_global_load_lds(
        (const __attribute__((address_space(1))) unsigned int*)g,
        (__attribute__((address_space(3))) unsigned int*)l, 16, 0, 0);
}

__global__ __launch_bounds__(256, 8) void bp_kernel(
    const unsigned int* __restrict__ pf, const float* __restrict__ vcs,
    const int* __restrict__ bs_tab, float* __restrict__ out) {
    __shared__ alignas(16) unsigned int s_buf[2 * 1024];  // 2 slots x 4096 B

    int t    = threadIdx.x;
    int zc   = blockIdx.z;
    int tile = blockIdx.y * TILES_X + blockIdx.x;
    int x    = blockIdx.x * 32 + (t & 31);
    int y    = blockIdx.y * 8 + (t >> 5);

    float X  = ((float)x - 207.5f) * (float)D_IMG_D;
    float Yv = (207.5f - (float)y) * (float)D_IMG_D;

    int vstart = (zc * VIEWS) / ZSPLIT;
    int vend   = ((zc + 1) * VIEWS) / ZSPLIT;
    int nv     = vend - vstart;
    const float4* vc4 = (const float4*)vcs + vstart;
    const int*    bsp = bs_tab + tile * VIEWS + vstart;
    const char*   pfb = (const char*)pf + (size_t)vstart * 40960; // 8*640*8 B/view
    int  goff  = (t >> 5) * (DETS * 8) + (t & 31) * 16;  // per-lane src offset
    int  ldoff = (t >> 6) << 10;                         // wave-uniform dst base

    float acc[32];
    #pragma unroll
    for (int b = 0; b < 32; ++b) acc[b] = 0.f;
    h2f hacc[16];
    #pragma unroll
    for (int p = 0; p < 16; ++p) hacc[p] = (h2f)0.f;

    #define STAGE(c) do { \
        int bsd = bsp[(c)]; \
        gld_lds16(pfb + (size_t)(c) * 40960 + (size_t)bsd * 8 + goff, \
                  (char*)s_buf + (((c) & 1) << 12) + ldoff); \
    } while (0)

    STAGE(0);
    __syncthreads();

    for (int c = 0; c < nv; ++c) {
        if (c + 1 < nv) STAGE(c + 1);

        float4 a  = vc4[c];
        int    bsc = bsp[c];
        float U   = fmaf(-X, a.x, fmaf(-Yv, a.y, (float)S2R_D));
        float num = fmaf(X, a.z, Yv * a.w);
        float ru   = __builtin_amdgcn_rcpf(U);
        float idx  = fmaf(num, ru, 319.5f);
        float idxc = __builtin_amdgcn_fmed3f(idx, 0.f, 639.f);
        float i0f  = fminf(idxc, 638.0f);
        int   i0   = (int)i0f;
        float frac = idxc - truncf(i0f);
        float w2   = ru * ru;
        float wgt  = (idx == idxc) ? w2 : 0.f;
        float w1f  = wgt * frac;
        float w0f  = wgt - w1f;
        h2f w0h = __builtin_amdgcn_cvt_pkrtz(w0f, w0f);
        h2f w1h = __builtin_amdgcn_cvt_pkrtz(w1f, w1f);
        int bl = min(max(i0 - bsc, 0), NB - 2);  // window-safe (wgt=0 if invalid)
        const uint2* L = (const uint2*)((const char*)s_buf + ((c & 1) << 12)) + bl;
        #pragma unroll
        for (int gg = 0; gg < 8; ++gg) {
            uint2 A = L[gg * NB];        // bin bl  : pairs (2g, 2g+1)
            uint2 B = L[gg * NB + 1];    // bin bl+1: pairs (2g, 2g+1)
            h2f pa = __builtin_bit_cast(h2f, A.x);
            h2f pb = __builtin_bit_cast(h2f, B.x);
            h2f pc = __builtin_bit_cast(h2f, A.y);
            h2f pd = __builtin_bit_cast(h2f, B.y);
            hacc[2 * gg]     = __builtin_elementwise_fma(pa, w0h, hacc[2 * gg]);
            hacc[2 * gg]     = __builtin_elementwise_fma(pb, w1h, hacc[2 * gg]);
            hacc[2 * gg + 1] = __builtin_elementwise_fma(pc, w0h, hacc[2 * gg + 1]);
            hacc[2 * gg + 1] = __builtin_elementwise_fma(pd, w1h, hacc[2 * gg + 1]);
        }
        if ((c & 7) == 7) {             // drain fp16 partials to fp32
            #pragma unroll
            for (int gg = 0; gg < 8; ++gg) {
                acc[4 * gg + 0] += (float)hacc[2 * gg].x;
                acc[4 * gg + 1] += (float)hacc[2 * gg].y;
                acc[4 * gg + 2] += (float)hacc[2 * gg + 1].x;
                acc[4 * gg + 3] += (float)hacc[2 * gg + 1].y;
                hacc[2 * gg] = (h2f)0.f; hacc[2 * gg + 1] = (h2f)0.f;
            }
        }
        __syncthreads();
    }
    #undef STAGE

    // epilogue drain (nv not a multiple of 8; harmless zeros otherwise)
    #pragma unroll
    for (int gg = 0; gg < 8; ++gg) {
        acc[4 * gg + 0] += (float)hacc[2 * gg].x;
        acc[4 * gg + 1] += (float)hacc[2 * gg].y;
        acc[4 * gg + 2] += (float)hacc[2 * gg + 1].x;
        acc[4 * gg + 3] += (float)hacc[2 * gg + 1].y;
    }

    float* ob = out + (size_t)y * W_IMG + x;
    #pragma unroll
    for (int b = 0; b < 32; ++b)
        unsafeAtomicAdd(ob + (size_t)b * (H_IMG * W_IMG), acc[b]);
}

// ---------------------------------------------------------------------------
extern "C" void kernel_launch(void* const* d_in, const int* in_sizes, int n_in,
                              void* d_out, int out_size, void* d_ws, size_t ws_size,
                              hipStream_t stream) {
    const float* proj = (const float*)d_in[0];   // [32,1,160,640]
    const float* w    = (const float*)d_in[1];   // [640]
    const float* filt = (const float*)d_in[2];   // [1279]
    float* out = (float*)d_out;                  // [32,1,416,416]

    float*        vcs    = (float*)d_ws;                         // 2560 B
    int*          bs_tab = (int*)((char*)d_ws + 4096);           // 432,640 B
    unsigned int* pf     = (unsigned int*)((char*)d_ws + 4096 + 432640); // 6.55 MB

    init_kernel<<<NTILES, 256, 0, stream>>>(vcs, bs_tab, (float4*)out);
    filter_kernel<<<(BATCH / 4) * VIEWS, FT, 0, stream>>>(proj, w, filt, pf);
    bp_kernel<<<dim3(TILES_X, TILES_Y, ZSPLIT), 256, 0, stream>>>(pf, vcs, bs_tab, out);
}